// Round 4
// baseline (267.961 us; speedup 1.0000x reference)
//
#include <hip/hip_runtime.h>
#include <hip/hip_cooperative_groups.h>

namespace cg = cooperative_groups;

#define HM_B 32
#define HM_C 98
#define HM_H 128
#define HM_W 128
#define HWSZ (HM_H * HM_W)          // 16384
#define FDIM 256
#define DDIM 128
#define NODE_F (2 + 1 + FDIM)       // 259
#define BC (HM_B * HM_C)            // 3136
#define HM_ELEMS ((size_t)BC * HWSZ)
#define LCHUNK 8                    // landmarks per embed unit (392 units)
#define ICHUNK 7                    // rows per gcn unit (448 units)
#define NBLK 512                    // 2 blocks/CU co-resident (VGPR<=256, 10KB LDS)
#define NTHR 256

typedef float f32x4 __attribute__((ext_vector_type(4)));

// ---------------- device helpers shared by both paths ----------------

__device__ __forceinline__ void argmax_copy_row(
    const float* __restrict__ hm, float* __restrict__ out_hm, int row, int tid,
    float* sv, int* si, int* __restrict__ idx_ws, float* __restrict__ conf_ws) {
    const f32x4* __restrict__ src = (const f32x4*)(hm + (size_t)row * HWSZ);
    f32x4* __restrict__ dst = (f32x4*)(out_hm + (size_t)row * HWSZ);
    float bv = -INFINITY;
    int bi = 0;
    #pragma unroll
    for (int t = 0; t < HWSZ / 4 / NTHR; ++t) {
        const int p = t * NTHR + tid;
        const f32x4 v = src[p];
        dst[p] = v;
        const float m4 = fmaxf(fmaxf(v[0], v[1]), fmaxf(v[2], v[3]));
        if (m4 > bv) {  // in-order scan keeps first occurrence within thread
            const int base = p * 4;
            if (v[0] > bv) { bv = v[0]; bi = base; }
            if (v[1] > bv) { bv = v[1]; bi = base + 1; }
            if (v[2] > bv) { bv = v[2]; bi = base + 2; }
            if (v[3] > bv) { bv = v[3]; bi = base + 3; }
        }
    }
    sv[tid] = bv; si[tid] = bi;
    __syncthreads();
    for (int s = NTHR / 2; s > 0; s >>= 1) {
        if (tid < s) {
            const float ov = sv[tid + s];
            const int oi = si[tid + s];
            if (ov > sv[tid] || (ov == sv[tid] && oi < si[tid])) {
                sv[tid] = ov; si[tid] = oi;
            }
        }
        __syncthreads();
    }
    if (tid == 0) { idx_ws[row] = si[0]; conf_ws[row] = sv[0]; }
    __syncthreads();
}

__device__ __forceinline__ void embed_unit(
    const float* __restrict__ feat, const int* __restrict__ idx_ws,
    const float* __restrict__ conf_ws, const float* __restrict__ W_embed,
    const float* __restrict__ b_embed, float* __restrict__ h0,
    int unit, int tid, float (*node)[NODE_F + 1]) {
    const int bc0 = unit * LCHUNK;
    #pragma unroll
    for (int l = 0; l < LCHUNK; ++l) {
        const int bcL = bc0 + l;
        const int b = bcL / HM_C;
        const int loc = idx_ws[bcL];                 // wave-uniform
        node[l][3 + tid] = feat[((size_t)(b * FDIM + tid)) * HWSZ + loc];
    }
    if (tid < LCHUNK) {
        const int bcL = bc0 + tid;
        const int loc = idx_ws[bcL];
        const int ys = loc / HM_W;
        const int xs = loc % HM_W;
        node[tid][0] = (float)xs / (float)HM_H;      // reference: [xs,ys]/[H,W]
        node[tid][1] = (float)ys / (float)HM_W;
        node[tid][2] = conf_ws[bcL];
    }
    __syncthreads();

    const int d = tid & (DDIM - 1);
    const int lbase = (tid >> 7) * 4;
    const float bias = b_embed[d];
    float acc0 = bias, acc1 = bias, acc2 = bias, acc3 = bias;
    for (int f = 0; f < NODE_F; ++f) {
        const float w = W_embed[f * DDIM + d];
        acc0 = fmaf(node[lbase + 0][f], w, acc0);
        acc1 = fmaf(node[lbase + 1][f], w, acc1);
        acc2 = fmaf(node[lbase + 2][f], w, acc2);
        acc3 = fmaf(node[lbase + 3][f], w, acc3);
    }
    h0[(size_t)(bc0 + lbase + 0) * DDIM + d] = fmaxf(acc0, 0.f);
    h0[(size_t)(bc0 + lbase + 1) * DDIM + d] = fmaxf(acc1, 0.f);
    h0[(size_t)(bc0 + lbase + 2) * DDIM + d] = fmaxf(acc2, 0.f);
    h0[(size_t)(bc0 + lbase + 3) * DDIM + d] = fmaxf(acc3, 0.f);
    __syncthreads();
}

__device__ __forceinline__ void gcn_unit(
    const float* __restrict__ A, const float* __restrict__ h0,
    const float* __restrict__ W_gcn, const float* __restrict__ W_out,
    const float* __restrict__ b_out, float* __restrict__ out2,
    int unit, int tid, char* smraw) {
    float* arow  = (float*)smraw;                    // 7*98*4  = 2744 B
    float* tmp_s = (float*)(smraw + 2752);           // 7*128*4 = 3584 B
    float* h1_s  = (float*)(smraw + 2752 + 3584);    // 7*128*4 = 3584 B
    const int b = unit / (HM_C / ICHUNK);
    const int i0 = (unit % (HM_C / ICHUNK)) * ICHUNK;

    for (int k = tid; k < ICHUNK * HM_C; k += NTHR)
        arow[k] = A[(i0 + k / HM_C) * HM_C + (k % HM_C)];
    __syncthreads();

    if (tid < DDIM) {
        float acc[ICHUNK];
        #pragma unroll
        for (int i = 0; i < ICHUNK; ++i) acc[i] = 0.f;
        for (int j = 0; j < HM_C; ++j) {
            const float v = h0[((size_t)b * HM_C + j) * DDIM + tid];
            #pragma unroll
            for (int i = 0; i < ICHUNK; ++i)
                acc[i] = fmaf(arow[i * HM_C + j], v, acc[i]);
        }
        #pragma unroll
        for (int i = 0; i < ICHUNK; ++i) tmp_s[i * DDIM + tid] = acc[i];
    }
    __syncthreads();

    if (tid < DDIM) {
        float acc[ICHUNK];
        #pragma unroll
        for (int i = 0; i < ICHUNK; ++i) acc[i] = 0.f;
        for (int k = 0; k < DDIM; ++k) {
            const float w = W_gcn[k * DDIM + tid];
            #pragma unroll
            for (int i = 0; i < ICHUNK; ++i)
                acc[i] = fmaf(tmp_s[i * DDIM + k], w, acc[i]);
        }
        #pragma unroll
        for (int i = 0; i < ICHUNK; ++i) h1_s[i * DDIM + tid] = fmaxf(acc[i], 0.f);
    }
    __syncthreads();

    if (tid < ICHUNK * 2) {
        const int i = tid >> 1;
        const int o = tid & 1;
        float acc = b_out[o];
        for (int dd = 0; dd < DDIM; ++dd)
            acc = fmaf(h1_s[i * DDIM + dd], W_out[dd * 2 + o], acc);
        out2[((size_t)b * HM_C + i0 + i) * 2 + o] = acc;
    }
    __syncthreads();
}

// ---------------- cooperative fused kernel ----------------

__global__ __launch_bounds__(NTHR, 2) void fused_kernel(
    const float* __restrict__ hm, const float* __restrict__ feat,
    const float* __restrict__ W_embed, const float* __restrict__ b_embed,
    const float* __restrict__ A, const float* __restrict__ W_gcn,
    const float* __restrict__ W_out, const float* __restrict__ b_out,
    float* __restrict__ out_hm, float* __restrict__ out2,
    int* __restrict__ idx_ws, float* __restrict__ conf_ws,
    float* __restrict__ h0_ws) {
    cg::grid_group grid = cg::this_grid();
    const int tid = threadIdx.x;
    __shared__ __align__(16) char smraw[10240];

    // Phase 1: copy + argmax
    {
        float* sv = (float*)smraw;
        int* si = (int*)(smraw + NTHR * sizeof(float));
        for (int row = blockIdx.x; row < BC; row += NBLK)
            argmax_copy_row(hm, out_hm, row, tid, sv, si, idx_ws, conf_ws);
    }
    grid.sync();

    // Phase 2: gather + embed (392 units)
    if (blockIdx.x < BC / LCHUNK)
        embed_unit(feat, idx_ws, conf_ws, W_embed, b_embed, h0_ws,
                   blockIdx.x, tid, (float (*)[NODE_F + 1])smraw);
    grid.sync();

    // Phase 3: GCN (448 units)
    if (blockIdx.x < HM_B * (HM_C / ICHUNK))
        gcn_unit(A, h0_ws, W_gcn, W_out, b_out, out2, blockIdx.x, tid, smraw);
}

// ---------------- fallback path (proven R2 structure) ----------------

__global__ __launch_bounds__(NTHR) void argmax_copy_kernel(
    const float* __restrict__ hm, float* __restrict__ out_hm,
    int* __restrict__ idx_ws, float* __restrict__ conf_ws) {
    __shared__ float sv[NTHR];
    __shared__ int si[NTHR];
    argmax_copy_row(hm, out_hm, blockIdx.x, threadIdx.x, sv, si, idx_ws, conf_ws);
}

__global__ __launch_bounds__(NTHR) void embed_kernel(
    const float* __restrict__ feat, const int* __restrict__ idx_ws,
    const float* __restrict__ conf_ws, const float* __restrict__ W_embed,
    const float* __restrict__ b_embed, float* __restrict__ h0) {
    __shared__ float node[LCHUNK][NODE_F + 1];
    embed_unit(feat, idx_ws, conf_ws, W_embed, b_embed, h0,
               blockIdx.x, threadIdx.x, node);
}

__global__ __launch_bounds__(NTHR) void gcn_kernel(
    const float* __restrict__ A, const float* __restrict__ h0,
    const float* __restrict__ W_gcn, const float* __restrict__ W_out,
    const float* __restrict__ b_out, float* __restrict__ out2) {
    __shared__ __align__(16) char smraw[10240];
    gcn_unit(A, h0, W_gcn, W_out, b_out, out2, blockIdx.x, threadIdx.x, smraw);
}

extern "C" void kernel_launch(void* const* d_in, const int* in_sizes, int n_in,
                              void* d_out, int out_size, void* d_ws, size_t ws_size,
                              hipStream_t stream) {
    const float* hm      = (const float*)d_in[0];
    const float* feat    = (const float*)d_in[1];
    const float* W_embed = (const float*)d_in[2];
    const float* b_embed = (const float*)d_in[3];
    const float* A       = (const float*)d_in[4];
    const float* W_gcn   = (const float*)d_in[5];
    const float* W_out   = (const float*)d_in[6];
    const float* b_out   = (const float*)d_in[7];

    float* out_hm = (float*)d_out;                 // [B,C,H,W] passthrough
    float* out2   = (float*)d_out + HM_ELEMS;      // [B,C,2]

    char* ws = (char*)d_ws;
    int*   idx_ws  = (int*)ws;    ws += BC * sizeof(int);
    float* conf_ws = (float*)ws;  ws += BC * sizeof(float);
    float* h0_ws   = (float*)ws;  // 1.606 MB; total ~1.63 MB (= R2's footprint)

    void* args[] = {(void*)&hm, (void*)&feat, (void*)&W_embed, (void*)&b_embed,
                    (void*)&A, (void*)&W_gcn, (void*)&W_out, (void*)&b_out,
                    (void*)&out_hm, (void*)&out2, (void*)&idx_ws, (void*)&conf_ws,
                    (void*)&h0_ws};
    hipError_t err = hipLaunchCooperativeKernel(
        reinterpret_cast<void*>(fused_kernel), dim3(NBLK), dim3(NTHR),
        args, 0, stream);

    if (err != hipSuccess) {
        // Fallback: proven three-kernel sequence (R2, 128.5 us)
        argmax_copy_kernel<<<BC, NTHR, 0, stream>>>(hm, out_hm, idx_ws, conf_ws);
        embed_kernel<<<BC / LCHUNK, NTHR, 0, stream>>>(feat, idx_ws, conf_ws,
                                                       W_embed, b_embed, h0_ws);
        gcn_kernel<<<HM_B * (HM_C / ICHUNK), NTHR, 0, stream>>>(
            A, h0_ws, W_gcn, W_out, b_out, out2);
    }
}

// Round 5
// 127.732 us; speedup vs baseline: 2.0978x; 2.0978x over previous
//
#include <hip/hip_runtime.h>

#define HM_B 32
#define HM_C 98
#define HM_H 128
#define HM_W 128
#define HWSZ (HM_H * HM_W)          // 16384
#define FDIM 256
#define DDIM 128
#define NODE_F (2 + 1 + FDIM)       // 259
#define NODE_P 260                  // padded row stride in node_ws
#define BC (HM_B * HM_C)            // 3136
#define HM_ELEMS ((size_t)BC * HWSZ)
#define LCHUNK 8                    // landmarks per embed block (392 blocks)
#define ICHUNK 7                    // rows per gcn block (448 blocks)
#define NTHR 256

typedef float f32x4 __attribute__((ext_vector_type(4)));

// Kernel 1: per (b,c) row — copy hm->out, argmax (first occurrence), then the
// block gathers the 256-dim feature vector at loc and emits the full node row.
// The scattered gather (one 64B line per thread) hides under the copy stream.
__global__ __launch_bounds__(NTHR) void k1_copy_argmax_gather(
    const float* __restrict__ hm, const float* __restrict__ feat,
    float* __restrict__ out_hm, float* __restrict__ node_ws) {
    const int row = blockIdx.x;
    const int tid = threadIdx.x;
    const f32x4* __restrict__ src = (const f32x4*)(hm + (size_t)row * HWSZ);
    f32x4* __restrict__ dst = (f32x4*)(out_hm + (size_t)row * HWSZ);

    float bv = -INFINITY;
    int bi = 0;
    #pragma unroll
    for (int t = 0; t < HWSZ / 4 / NTHR; ++t) {
        const int p = t * NTHR + tid;
        const f32x4 v = __builtin_nontemporal_load(src + p);
        __builtin_nontemporal_store(v, dst + p);
        const float m4 = fmaxf(fmaxf(v[0], v[1]), fmaxf(v[2], v[3]));
        if (m4 > bv) {  // in-order scan keeps first occurrence within thread
            const int base = p * 4;
            if (v[0] > bv) { bv = v[0]; bi = base; }
            if (v[1] > bv) { bv = v[1]; bi = base + 1; }
            if (v[2] > bv) { bv = v[2]; bi = base + 2; }
            if (v[3] > bv) { bv = v[3]; bi = base + 3; }
        }
    }

    __shared__ float sv[NTHR];
    __shared__ int si[NTHR];
    sv[tid] = bv; si[tid] = bi;
    __syncthreads();
    for (int s = NTHR / 2; s > 0; s >>= 1) {
        if (tid < s) {
            const float ov = sv[tid + s];
            const int oi = si[tid + s];
            if (ov > sv[tid] || (ov == sv[tid] && oi < si[tid])) {
                sv[tid] = ov; si[tid] = oi;
            }
        }
        __syncthreads();
    }

    const int loc = si[0];
    const float conf = sv[0];
    const int b = row / HM_C;
    // one scattered 64B-line load per thread; latency hidden by other blocks
    const float vis = feat[((size_t)(b * FDIM + tid)) * HWSZ + loc];
    float* nrow = node_ws + (size_t)row * NODE_P;
    nrow[3 + tid] = vis;
    if (tid == 0) {
        nrow[0] = (float)(loc % HM_W) * (1.0f / (float)HM_H);  // ref: [xs,ys]/[H,W]
        nrow[1] = (float)(loc / HM_W) * (1.0f / (float)HM_W);
        nrow[2] = conf;
    }
}

// Kernel 2: h0 = relu(node @ W_embed + b_embed), 8 landmarks/block.
// Writes h0 IN-PLACE over node_ws[row][0:128] (row fully staged to LDS first;
// no other block reads this row).
__global__ __launch_bounds__(NTHR) void k2_embed(
    float* __restrict__ node_ws, const float* __restrict__ W_embed,
    const float* __restrict__ b_embed) {
    const int bc0 = blockIdx.x * LCHUNK;
    const int tid = threadIdx.x;
    __shared__ float node_s[LCHUNK][NODE_P];  // 8*260*4 = 8320 B

    #pragma unroll
    for (int l = 0; l < LCHUNK; ++l)
        for (int k = tid; k < NODE_F; k += NTHR)
            node_s[l][k] = node_ws[(size_t)(bc0 + l) * NODE_P + k];
    __syncthreads();

    const int d = tid & (DDIM - 1);
    const int lbase = (tid >> 7) * 4;
    const float bias = b_embed[d];
    float a0 = bias, a1 = bias, a2 = bias, a3 = bias;
    for (int f = 0; f < NODE_F; ++f) {
        const float w = W_embed[f * DDIM + d];
        a0 = fmaf(node_s[lbase + 0][f], w, a0);
        a1 = fmaf(node_s[lbase + 1][f], w, a1);
        a2 = fmaf(node_s[lbase + 2][f], w, a2);
        a3 = fmaf(node_s[lbase + 3][f], w, a3);
    }
    node_ws[(size_t)(bc0 + lbase + 0) * NODE_P + d] = fmaxf(a0, 0.f);
    node_ws[(size_t)(bc0 + lbase + 1) * NODE_P + d] = fmaxf(a1, 0.f);
    node_ws[(size_t)(bc0 + lbase + 2) * NODE_P + d] = fmaxf(a2, 0.f);
    node_ws[(size_t)(bc0 + lbase + 3) * NODE_P + d] = fmaxf(a3, 0.f);
}

// Kernel 3: h1 = relu((A @ h0) @ W_gcn); out2 = h1 @ W_out + b_out.
// h0 lives in node_ws rows (stride NODE_P), L2/L3-resident.
__global__ __launch_bounds__(DDIM) void k3_gcn(
    const float* __restrict__ A, const float* __restrict__ node_ws,
    const float* __restrict__ W_gcn, const float* __restrict__ W_out,
    const float* __restrict__ b_out, float* __restrict__ out2) {
    const int b = blockIdx.x / (HM_C / ICHUNK);
    const int i0 = (blockIdx.x % (HM_C / ICHUNK)) * ICHUNK;
    const int tid = threadIdx.x;           // = d

    __shared__ float arow[ICHUNK * HM_C];  // 2744 B
    __shared__ float tmp_s[ICHUNK * DDIM]; // 3584 B
    __shared__ float h1_s[ICHUNK * DDIM];  // 3584 B

    for (int k = tid; k < ICHUNK * HM_C; k += DDIM)
        arow[k] = A[(i0 + k / HM_C) * HM_C + (k % HM_C)];
    __syncthreads();

    {
        float acc[ICHUNK];
        #pragma unroll
        for (int i = 0; i < ICHUNK; ++i) acc[i] = 0.f;
        for (int j = 0; j < HM_C; ++j) {
            const float v = node_ws[((size_t)b * HM_C + j) * NODE_P + tid];
            #pragma unroll
            for (int i = 0; i < ICHUNK; ++i)
                acc[i] = fmaf(arow[i * HM_C + j], v, acc[i]);
        }
        #pragma unroll
        for (int i = 0; i < ICHUNK; ++i) tmp_s[i * DDIM + tid] = acc[i];
    }
    __syncthreads();

    {
        float acc[ICHUNK];
        #pragma unroll
        for (int i = 0; i < ICHUNK; ++i) acc[i] = 0.f;
        for (int k = 0; k < DDIM; ++k) {
            const float w = W_gcn[k * DDIM + tid];
            #pragma unroll
            for (int i = 0; i < ICHUNK; ++i)
                acc[i] = fmaf(tmp_s[i * DDIM + k], w, acc[i]);
        }
        #pragma unroll
        for (int i = 0; i < ICHUNK; ++i) h1_s[i * DDIM + tid] = fmaxf(acc[i], 0.f);
    }
    __syncthreads();

    if (tid < ICHUNK * 2) {
        const int i = tid >> 1;
        const int o = tid & 1;
        float acc = b_out[o];
        for (int dd = 0; dd < DDIM; ++dd)
            acc = fmaf(h1_s[i * DDIM + dd], W_out[dd * 2 + o], acc);
        out2[((size_t)b * HM_C + i0 + i) * 2 + o] = acc;
    }
}

extern "C" void kernel_launch(void* const* d_in, const int* in_sizes, int n_in,
                              void* d_out, int out_size, void* d_ws, size_t ws_size,
                              hipStream_t stream) {
    const float* hm      = (const float*)d_in[0];
    const float* feat    = (const float*)d_in[1];
    const float* W_embed = (const float*)d_in[2];
    const float* b_embed = (const float*)d_in[3];
    const float* A       = (const float*)d_in[4];
    const float* W_gcn   = (const float*)d_in[5];
    const float* W_out   = (const float*)d_in[6];
    const float* b_out   = (const float*)d_in[7];

    float* out_hm = (float*)d_out;                 // [B,C,H,W] passthrough
    float* out2   = (float*)d_out + HM_ELEMS;      // [B,C,2]

    float* node_ws = (float*)d_ws;                 // BC x NODE_P = 3.26 MB total

    k1_copy_argmax_gather<<<BC, NTHR, 0, stream>>>(hm, feat, out_hm, node_ws);
    k2_embed<<<BC / LCHUNK, NTHR, 0, stream>>>(node_ws, W_embed, b_embed);
    k3_gcn<<<HM_B * (HM_C / ICHUNK), DDIM, 0, stream>>>(A, node_ws, W_gcn,
                                                        W_out, b_out, out2);
}